// Round 1
// baseline (99.956 us; speedup 1.0000x reference)
//
#include <hip/hip_runtime.h>
#include <hip/hip_bf16.h>
#include <hip/hip_fp16.h>
#include <stdint.h>

typedef __attribute__((ext_vector_type(8))) _Float16 f16x8;
typedef __attribute__((ext_vector_type(4))) float f32x4;
typedef __attribute__((ext_vector_type(4))) int i32x4;

#define GLD_LDS16(g, l) __builtin_amdgcn_global_load_lds( \
    (const __attribute__((address_space(1))) uint32_t*)(g), \
    (__attribute__((address_space(3))) uint32_t*)(l), 16, 0, 0)

// ---------------- W fp32 -> fp16 (into workspace), 512x2048 -------------
__global__ __launch_bounds__(256) void k_cvt_w(const float* __restrict__ W,
                                               _Float16* __restrict__ Wh) {
  int i = (blockIdx.x * 256 + threadIdx.x) * 8;  // 1048576 elems total
  float4 a = *(const float4*)(W + i);
  float4 b = *(const float4*)(W + i + 4);
  union { _Float16 h[8]; i32x4 v; } u;
  u.h[0] = (_Float16)a.x; u.h[1] = (_Float16)a.y;
  u.h[2] = (_Float16)a.z; u.h[3] = (_Float16)a.w;
  u.h[4] = (_Float16)b.x; u.h[5] = (_Float16)b.y;
  u.h[6] = (_Float16)b.z; u.h[7] = (_Float16)b.w;
  *(i32x4*)(Wh + i) = u.v;
}

__device__ inline float softplus_f(float x) {
  float e = __expf(-fabsf(x));
  return fmaxf(x, 0.f) + __logf(1.f + e);
}

// ---------------- fused GEMM(fp16x2 MFMA) + softplus-diff + sigmoid ------
// Block: 64 rows x 512 cols(hid), K=2048 in steps of 64. 8 waves, each 64x64.
__global__ __launch_bounds__(512, 2) void k_main(
    const float* __restrict__ X,      // [16384][2048]
    const _Float16* __restrict__ Wh,  // [512][2048]
    const float* __restrict__ U,      // [512][2]
    const float* __restrict__ hb,     // [512]
    const float* __restrict__ yb,     // [2]
    float* __restrict__ out) {        // [16384][2]
  __shared__ __align__(16) _Float16 Ah[64 * 64];
  __shared__ __align__(16) _Float16 Al[64 * 64];
  __shared__ __align__(16) _Float16 Bs[512 * 64];
  __shared__ float sD[64];

  const int t = threadIdx.x;
  const int lane = t & 63;
  const int wid = t >> 6;
  const int bm0 = blockIdx.x * 64;
  const int lrow = lane & 15, lq = lane >> 4;

  if (t < 64) sD[t] = 0.f;

  f32x4 acc[4][4];
#pragma unroll
  for (int i = 0; i < 4; ++i)
#pragma unroll
    for (int j = 0; j < 4; ++j) acc[i][j] = (f32x4){0.f, 0.f, 0.f, 0.f};

  // A staging geometry: thread t -> row t>>3, 8-half chunk t&7. XOR swizzle
  // ((row&7)<<4) on the 16B slot so frag ds_read_b128 is ~conflict-free (G4).
  const int arow = t >> 3, akg = t & 7;
  const float* xptr = X + (size_t)(bm0 + arow) * 2048 + akg * 8;
  char* ah_w = (char*)Ah + arow * 128 + (((akg ^ (arow & 7))) << 4);
  char* al_w = (char*)Al + arow * 128 + (((akg ^ (arow & 7))) << 4);

  // B staging: per wave 8 issues of global_load_lds covering 8 rows each.
  // LDS dest is linear (wave base + lane*16); swizzle applied by permuting
  // the per-lane GLOBAL source chunk (m173 pattern): phys slot s holds
  // logical chunk s ^ (row&7).
  const int r8 = lane >> 3, s8 = lane & 7;
  const _Float16* wptr = Wh + (size_t)(wid * 64 + r8) * 2048 + ((s8 ^ r8) << 3);
  char* bs_w = (char*)Bs + (wid * 64) * 128;

  for (int kt = 0; kt < 32; ++kt) {
    const int k0 = kt * 64;
    __syncthreads();  // previous compute done before overwrite
#pragma unroll
    for (int i = 0; i < 8; ++i) {
      GLD_LDS16(wptr + (size_t)i * 8 * 2048 + k0, bs_w + i * 1024);
    }
    float4 f0 = *(const float4*)(xptr + k0);
    float4 f1 = *(const float4*)(xptr + k0 + 4);
    union { _Float16 h[8]; i32x4 v; } uh, ul;
    float fv[8] = {f0.x, f0.y, f0.z, f0.w, f1.x, f1.y, f1.z, f1.w};
#pragma unroll
    for (int j = 0; j < 8; ++j) {
      _Float16 hi = (_Float16)fv[j];
      uh.h[j] = hi;
      ul.h[j] = (_Float16)(fv[j] - (float)hi);
    }
    *(i32x4*)ah_w = uh.v;
    *(i32x4*)al_w = ul.v;
    __syncthreads();  // drains vmcnt(0): global_load_lds data landed

#pragma unroll
    for (int ks = 0; ks < 2; ++ks) {
      const int koff = ks * 64 + lq * 16;
      f16x8 a_h[4], a_l[4], b_f[4];
#pragma unroll
      for (int mf = 0; mf < 4; ++mf) {
        int row = mf * 16 + lrow;
        int off = row * 128 + (koff ^ ((row & 7) << 4));
        a_h[mf] = *(const f16x8*)((const char*)Ah + off);
        a_l[mf] = *(const f16x8*)((const char*)Al + off);
      }
#pragma unroll
      for (int nf = 0; nf < 4; ++nf) {
        int row = wid * 64 + nf * 16 + lrow;
        int off = row * 128 + (koff ^ ((row & 7) << 4));
        b_f[nf] = *(const f16x8*)((const char*)Bs + off);
      }
#pragma unroll
      for (int mf = 0; mf < 4; ++mf)
#pragma unroll
        for (int nf = 0; nf < 4; ++nf) {
          acc[mf][nf] = __builtin_amdgcn_mfma_f32_16x16x32_f16(
              a_h[mf], b_f[nf], acc[mf][nf], 0, 0, 0);
          acc[mf][nf] = __builtin_amdgcn_mfma_f32_16x16x32_f16(
              a_l[mf], b_f[nf], acc[mf][nf], 0, 0, 0);
        }
    }
  }

  // Epilogue: per-lane softplus-difference partials.
  // acc[mf][nf][r] is pf at row (16*mf + lq*4 + r), col (64*wid + 16*nf + lrow)
  float dpart[16];
#pragma unroll
  for (int i = 0; i < 16; ++i) dpart[i] = 0.f;
#pragma unroll
  for (int nf = 0; nf < 4; ++nf) {
    int h = wid * 64 + nf * 16 + lrow;
    float hbv = hb[h];
    float u0 = U[2 * h], u1 = U[2 * h + 1];
#pragma unroll
    for (int mf = 0; mf < 4; ++mf)
#pragma unroll
      for (int r = 0; r < 4; ++r) {
        float pf = acc[mf][nf][r] + hbv;
        dpart[mf * 4 + r] += softplus_f(pf + u0) - softplus_f(pf + u1);
      }
  }
  // reduce across the 16 col-lanes (l&15); masks 1,2,4,8 stay in-group
#pragma unroll
  for (int i = 0; i < 16; ++i) {
    float v = dpart[i];
    v += __shfl_xor(v, 1);
    v += __shfl_xor(v, 2);
    v += __shfl_xor(v, 4);
    v += __shfl_xor(v, 8);
    dpart[i] = v;
  }
  if (lrow == 0) {
#pragma unroll
    for (int mf = 0; mf < 4; ++mf)
#pragma unroll
      for (int r = 0; r < 4; ++r)
        atomicAdd(&sD[mf * 16 + lq * 4 + r], dpart[mf * 4 + r]);
  }
  __syncthreads();
  if (t < 64) {
    float Dl = sD[t] + yb[0] - yb[1];  // logit0 - logit1
    float o0 = 1.f / (1.f + __expf(-Dl));
    float o1 = 1.f / (1.f + __expf(Dl));
    float2* op = (float2*)(out + (size_t)(bm0 + t) * 2);
    *op = make_float2(o0, o1);
  }
}

extern "C" void kernel_launch(void* const* d_in, const int* in_sizes, int n_in,
                              void* d_out, int out_size, void* d_ws,
                              size_t ws_size, hipStream_t stream) {
  const float* X = (const float*)d_in[0];
  const float* W = (const float*)d_in[1];
  const float* U = (const float*)d_in[2];
  const float* hb = (const float*)d_in[3];
  const float* yb = (const float*)d_in[4];
  float* out = (float*)d_out;
  _Float16* Wh = (_Float16*)d_ws;  // 512*2048*2 = 2 MB scratch

  hipLaunchKernelGGL(k_cvt_w, dim3(512), dim3(256), 0, stream, W, Wh);
  hipLaunchKernelGGL(k_main, dim3(256), dim3(512), 0, stream, X, Wh, U, hb, yb,
                     out);
}